// Round 13
// baseline (469.002 us; speedup 1.0000x reference)
//
#include <hip/hip_runtime.h>
#include <stdint.h>

#define NNODES 50000
#define NEDGES 800000
#define DIM 128
#define IN1 512
#define IN2 384
#define NSB 196   // ceil(NNODES/256)

typedef __attribute__((ext_vector_type(8))) short bf16x8;
typedef __attribute__((ext_vector_type(8))) unsigned short u16x8;
typedef __attribute__((ext_vector_type(4))) float f32x4;
typedef __attribute__((ext_vector_type(4))) uint32_t u32x4;
typedef __attribute__((ext_vector_type(2))) uint32_t u32x2;

__device__ __forceinline__ unsigned short f2bf(float f) {
  union { float f; uint32_t u; } v; v.f = f;
  return (unsigned short)((v.u + 0x7FFFu + ((v.u >> 16) & 1u)) >> 16);
}
__device__ __forceinline__ float bf2f(unsigned short u) {
  union { uint32_t u; float f; } v; v.u = ((uint32_t)u) << 16;
  return v.f;
}
__device__ __forceinline__ float bf2f_lo(uint32_t u) {
  union { uint32_t u; float f; } v; v.u = u << 16;
  return v.f;
}
__device__ __forceinline__ float bf2f_hi(uint32_t u) {
  union { uint32_t u; float f; } v; v.u = u & 0xFFFF0000u;
  return v.f;
}
__device__ __forceinline__ uint32_t cvtpk(float lo, float hi) {
  uint32_t r;
  asm volatile("v_cvt_pk_bf16_f32 %0, %1, %2" : "=v"(r) : "v"(lo), "v"(hi));
  return r;
}

__device__ __forceinline__ void cvt8(const float* __restrict__ p, unsigned short* dst, int sidx) {
  float4 f0 = *(const float4*)(p);
  float4 f1 = *(const float4*)(p + 4);
  u16x8 o;
  o[0] = f2bf(f0.x); o[1] = f2bf(f0.y); o[2] = f2bf(f0.z); o[3] = f2bf(f0.w);
  o[4] = f2bf(f1.x); o[5] = f2bf(f1.y); o[6] = f2bf(f1.z); o[7] = f2bf(f1.w);
  *(u16x8*)(dst + sidx) = o;
}

// 128x128x128 macro-tile, 4 waves as 2x2 of 64x64
__device__ __forceinline__ void mfma128(const unsigned short* As, const unsigned short* Bs,
                                        f32x4 acc[4][4], int wm, int wn, int l) {
#pragma unroll
  for (int kk = 0; kk < 4; ++kk) {
    bf16x8 a[4], b[4];
#pragma unroll
    for (int mi = 0; mi < 4; ++mi) {
      int row = wm * 64 + mi * 16 + (l & 15);
      int idx = (row * 128 + kk * 32 + (l >> 4) * 8) ^ ((row & 7) << 3);
      a[mi] = *(const bf16x8*)(As + idx);
    }
#pragma unroll
    for (int ni = 0; ni < 4; ++ni) {
      int nrow = wn * 64 + ni * 16 + (l & 15);
      int idx = (nrow * 128 + kk * 32 + (l >> 4) * 8) ^ ((nrow & 7) << 3);
      b[ni] = *(const bf16x8*)(Bs + idx);
    }
#pragma unroll
    for (int mi = 0; mi < 4; ++mi)
#pragma unroll
      for (int ni = 0; ni < 4; ++ni)
        acc[mi][ni] = __builtin_amdgcn_mfma_f32_16x16x32_bf16(a[mi], b[ni], acc[mi][ni], 0, 0, 0);
  }
}

// ---------------- zero: count (+ optional float4 array for fallback path) ----------------
__global__ void zero_kernel(float4* __restrict__ a, int n4, int* __restrict__ c, int nc) {
  int i = blockIdx.x * 256 + threadIdx.x;
  int stride = gridDim.x * 256;
  for (int k = i; k < n4; k += stride) a[k] = float4{0.f, 0.f, 0.f, 0.f};
  for (int k = i; k < nc; k += stride) c[k] = 0;
}

// ---------------- wconv+p0: 5 pre-swizzled bf16 weight tiles, plus Ud/Uc ----------------
__global__ void wconv_p0_kernel(const float* __restrict__ W1, const float* __restrict__ W2,
                                const float* __restrict__ u, const float* __restrict__ b1,
                                const float* __restrict__ b2,
                                unsigned short* __restrict__ Wt,
                                float* __restrict__ Ud, float* __restrict__ Uc) {
  int b = blockIdx.x;
  if (b < 320) {
    int t = b * 256 + threadIdx.x;
    int tile = t >> 14, rem = t & 16383, n = rem >> 7, k = rem & 127;
    float v = (tile < 3) ? W1[(size_t)n * IN1 + tile * 128 + k]
                         : W2[(size_t)n * IN2 + (tile - 3) * 128 + k];
    int lin = ((n * 128 + (k & ~7)) ^ ((n & 7) << 3)) | (k & 7);
    Wt[tile * 16384 + lin] = f2bf(v);
  } else {
    int g = (b - 320) * 2 + (threadIdx.x >> 7);
    int c = threadIdx.x & 127;
    const float* ur = u + (size_t)g * DIM;
    const float* w1 = W1 + (size_t)c * IN1 + 384;
    const float* w2 = W2 + (size_t)c * IN2 + 256;
    float s1 = b1[c], s2 = b2[c];
    for (int k = 0; k < DIM; ++k) { float uv = ur[k]; s1 += uv * w1[k]; s2 += uv * w2[k]; }
    Ud[g * DIM + c] = s1;
    Uc[g * DIM + c] = s2;
  }
}

// ---------------- P1: Xad/Xb/Yx per-node precompute (linear coalesced staging) ----------------
__global__ __launch_bounds__(256, 2) void p1_kernel(
    const float* __restrict__ x, const int* __restrict__ batch,
    const unsigned short* __restrict__ Wt,
    const float* __restrict__ Ud, const float* __restrict__ Uc,
    unsigned short* __restrict__ Xad, unsigned short* __restrict__ Xb,
    unsigned short* __restrict__ Yx) {
  __shared__ __align__(16) unsigned short As[128 * 128];
  __shared__ __align__(16) unsigned short Bs[128 * 128];
  const int t = threadIdx.x, l = t & 63, w = t >> 6, wm = w >> 1, wn = w & 1;
  const int n0 = blockIdx.x * 128;
#pragma unroll
  for (int i = 0; i < 16; ++i) {
    int idx = i * 256 + t;
    int row = idx >> 5;
    int c = (idx & 31) * 4;
    int n = n0 + row; if (n >= NNODES) n = NNODES - 1;
    float4 f = *(const float4*)(x + (size_t)n * DIM + c);
    u32x2 g = {cvtpk(f.x, f.y), cvtpk(f.z, f.w)};
    *(u32x2*)(As + (row * 128 + (c ^ ((row & 7) << 3)))) = g;
  }
#pragma unroll
  for (int p = 0; p < 3; ++p) {
    __syncthreads();
    {
      const u16x8* wsrc = (const u16x8*)(Wt + (size_t)((p == 2) ? 3 : p) * 16384);
      u16x8* bdst = (u16x8*)Bs;
#pragma unroll
      for (int i = 0; i < 8; ++i) bdst[t + i * 256] = wsrc[t + i * 256];
    }
    __syncthreads();
    f32x4 acc[4][4] = {};
    mfma128(As, Bs, acc, wm, wn, l);
#pragma unroll
    for (int mi = 0; mi < 4; ++mi)
#pragma unroll
      for (int rr = 0; rr < 4; ++rr) {
        int m = wm * 64 + mi * 16 + (l >> 4) * 4 + rr;
        int n = n0 + m;
        if (n < NNODES) {
          int g = batch[n];
#pragma unroll
          for (int ni = 0; ni < 4; ++ni) {
            int col = wn * 64 + ni * 16 + (l & 15);
            float v = acc[mi][ni][rr];
            if (p == 0)      Xad[(size_t)n * DIM + col] = f2bf(v + Ud[g * DIM + col]);
            else if (p == 1) Xb [(size_t)n * DIM + col] = f2bf(v);
            else             Yx [(size_t)n * DIM + col] = f2bf(v + Uc[g * DIM + col]);
          }
        }
      }
  }
}

// ---------------- counting sort by dst ----------------
__global__ void hist_kernel(const int* __restrict__ dstI, int* __restrict__ count) {
  int e = blockIdx.x * 256 + threadIdx.x;
  if (e < NEDGES) atomicAdd(&count[dstI[e]], 1);
}

__global__ void scan1_kernel(const int* __restrict__ count, int* __restrict__ bsum) {
  __shared__ int ws[4];
  int i = blockIdx.x * 256 + threadIdx.x;
  int v = (i < NNODES) ? count[i] : 0;
  int l = threadIdx.x & 63;
#pragma unroll
  for (int off = 32; off > 0; off >>= 1) v += __shfl_down(v, off);
  if (l == 0) ws[threadIdx.x >> 6] = v;
  __syncthreads();
  if (threadIdx.x == 0) bsum[blockIdx.x] = ws[0] + ws[1] + ws[2] + ws[3];
}

__global__ void scan2_kernel(const int* __restrict__ bsum, int* __restrict__ bpre) {
  __shared__ int s[256];
  int i = threadIdx.x;
  int v = (i < NSB) ? bsum[i] : 0;
  s[i] = v; __syncthreads();
  for (int off = 1; off < 256; off <<= 1) {
    int u = (i >= off) ? s[i - off] : 0;
    __syncthreads();
    s[i] += u;
    __syncthreads();
  }
  if (i < NSB) bpre[i] = s[i] - v;   // exclusive
}

__global__ void scan3_kernel(const int* __restrict__ count, const int* __restrict__ bpre,
                             int* __restrict__ rowptr) {
  __shared__ int s[256];
  int b = blockIdx.x, i = threadIdx.x, g = b * 256 + i;
  int v = (g < NNODES) ? count[g] : 0;
  s[i] = v; __syncthreads();
  for (int off = 1; off < 256; off <<= 1) {
    int u = (i >= off) ? s[i - off] : 0;
    __syncthreads();
    s[i] += u;
    __syncthreads();
  }
  if (g < NNODES) rowptr[g] = bpre[b] + s[i] - v;  // exclusive global prefix
}

// destructive on rowptr (becomes inclusive end); order[pos] = e
__global__ void scatter_kernel(const int* __restrict__ dstI,
                               int* __restrict__ rowptr, int* __restrict__ order) {
  int e = blockIdx.x * 256 + threadIdx.x;
  if (e < NEDGES) {
    int d = dstI[e];
    int pos = atomicAdd(&rowptr[d], 1);
    order[pos] = e;
  }
}

// ---------------- edgeA: fully-streaming edge GEMM in ORIGINAL order ----------------
// msg[e] = bf16( relu( ea[e]@W1c^T + Xad[dst[e]] + Xb[src[e]] ) )
__global__ __launch_bounds__(256, 2) void edgeA_kernel(
    const float* __restrict__ ea, const int* __restrict__ srcI, const int* __restrict__ dstI,
    const unsigned short* __restrict__ W1cs,
    const unsigned short* __restrict__ Xad, const unsigned short* __restrict__ Xb,
    unsigned short* __restrict__ msg) {
  __shared__ __align__(16) unsigned short As[128 * 128];   // 32KB; Ms aliases post-MFMA
  __shared__ __align__(16) unsigned short Bs[128 * 128];   // 32KB W1c
  __shared__ int dl[128];
  __shared__ int sl[128];
  unsigned short* Ms = As;

  const int t = threadIdx.x, l = t & 63, w = t >> 6, wm = w >> 1, wn = w & 1;
  const int e0 = blockIdx.x * 128;

  // ---- stage A: fully sequential read of 128 consecutive ea rows (64KB) ----
#pragma unroll
  for (int i = 0; i < 16; ++i) {
    int idx = i * 256 + t;               // float4 index within tile
    int row = idx >> 5;
    int c = (idx & 31) * 4;
    float4 f = *(const float4*)(ea + (size_t)e0 * DIM + (size_t)idx * 4);
    u32x2 g = {cvtpk(f.x, f.y), cvtpk(f.z, f.w)};
    *(u32x2*)(As + (row * 128 + (c ^ ((row & 7) << 3)))) = g;
  }
  // ---- stage B: raw copy of pre-swizzled W1c ----
  {
    const u16x8* wsrc = (const u16x8*)W1cs;
    u16x8* bdst = (u16x8*)Bs;
#pragma unroll
    for (int i = 0; i < 8; ++i) bdst[t + i * 256] = wsrc[t + i * 256];
  }
  if (t < 128) { dl[t] = dstI[e0 + t]; sl[t] = srcI[e0 + t]; }
  __syncthreads();

  f32x4 acc[4][4] = {};
  mfma128(As, Bs, acc, wm, wn, l);
  __syncthreads();   // As dead -> Ms writable

  // ---- epilogue: relu(acc + Xad[dst] + Xb[src]) -> Ms (bf16, swizzled) ----
#pragma unroll
  for (int mi = 0; mi < 4; ++mi)
#pragma unroll
    for (int rr = 0; rr < 4; ++rr) {
      int m = wm * 64 + mi * 16 + (l >> 4) * 4 + rr;
      int d = dl[m], s = sl[m];
      const unsigned short* xa = Xad + (size_t)d * DIM;
      const unsigned short* xb = Xb + (size_t)s * DIM;
      int cx = ((m >> 2) & 3) << 4;
#pragma unroll
      for (int ni = 0; ni < 4; ++ni) {
        int col = wn * 64 + ni * 16 + (l & 15);
        float v = acc[mi][ni][rr] + bf2f(xa[col]) + bf2f(xb[col]);
        Ms[m * 128 + (col ^ cx)] = f2bf(fmaxf(v, 0.0f));
      }
    }
  __syncthreads();

  // ---- write out: fully coalesced sequential store of 32KB tile ----
#pragma unroll
  for (int j = 0; j < 8; ++j) {
    int cidx = j * 256 + t;              // u16x8 chunk index (2048 total)
    int row = cidx >> 4;
    int off = (cidx & 15) * 8;
    u16x8 vv = *(const u16x8*)(Ms + row * 128 + (off ^ (((row >> 2) & 3) << 4)));
    *(u16x8*)(msg + (size_t)(e0 + row) * DIM + off) = vv;
  }
}

// ---------------- aggB: per-node segment reduce over L3-resident msg ----------------
// agg[n] = sum_{k in [beg,end)} msg[order[k]]   (4 nodes per wave, 16 per block)
__global__ __launch_bounds__(256, 8) void aggB_kernel(
    const unsigned short* __restrict__ msg, const int* __restrict__ order,
    const int* __restrict__ rowend, float* __restrict__ agg) {
  int gw = blockIdx.x * 4 + (threadIdx.x >> 6);   // global wave 0..12499
  int l = threadIdx.x & 63;
#pragma unroll
  for (int ii = 0; ii < 4; ++ii) {
    int n = gw * 4 + ii;
    if (n >= NNODES) break;
    int beg = (n == 0) ? 0 : rowend[n - 1];
    int end = rowend[n];
    float a0 = 0.f, a1 = 0.f;
    int k = beg;
    for (; k + 1 < end; k += 2) {
      int e0 = order[k], e1 = order[k + 1];
      uint32_t v0 = ((const uint32_t*)(msg + (size_t)e0 * DIM))[l];
      uint32_t v1 = ((const uint32_t*)(msg + (size_t)e1 * DIM))[l];
      a0 += bf2f_lo(v0) + bf2f_lo(v1);
      a1 += bf2f_hi(v0) + bf2f_hi(v1);
    }
    if (k < end) {
      int e0 = order[k];
      uint32_t v0 = ((const uint32_t*)(msg + (size_t)e0 * DIM))[l];
      a0 += bf2f_lo(v0);
      a1 += bf2f_hi(v0);
    }
    float2 o; o.x = a0; o.y = a1;
    *(float2*)(agg + (size_t)n * DIM + 2 * l) = o;
  }
}

// ---------------- edge (unsorted fallback, atomics) ----------------
__global__ __launch_bounds__(256, 2) void edge_kernel(
    const float* __restrict__ ea, const int* __restrict__ srcI, const int* __restrict__ dstI,
    const unsigned short* __restrict__ W1cs,
    const unsigned short* __restrict__ Xad, const unsigned short* __restrict__ Xb,
    float* __restrict__ agg) {
  __shared__ __align__(16) unsigned short As[128 * 128];
  __shared__ __align__(16) unsigned short Bs[128 * 128];
  const int t = threadIdx.x, l = t & 63, w = t >> 6, wm = w >> 1, wn = w & 1;
  const int e0 = blockIdx.x * 128, r = t >> 1, h = t & 1;
  const int swz = (r & 7) << 3;
  {
    const float* rowp = ea + (size_t)(e0 + r) * DIM + h * 64;
#pragma unroll
    for (int i = 0; i < 8; ++i) cvt8(rowp + i * 8, As, (r * 128 + h * 64 + i * 8) ^ swz);
  }
  {
    const u16x8* wsrc = (const u16x8*)W1cs;
    u16x8* bdst = (u16x8*)Bs;
#pragma unroll
    for (int i = 0; i < 8; ++i) bdst[t + i * 256] = wsrc[t + i * 256];
  }
  __syncthreads();
  f32x4 acc[4][4] = {};
  mfma128(As, Bs, acc, wm, wn, l);
#pragma unroll
  for (int mi = 0; mi < 4; ++mi)
#pragma unroll
    for (int rr = 0; rr < 4; ++rr) {
      int m = wm * 64 + mi * 16 + (l >> 4) * 4 + rr;
      int e = e0 + m;
      int d = dstI[e], s = srcI[e];
      const unsigned short* xa = Xad + (size_t)d * DIM;
      const unsigned short* xb = Xb + (size_t)s * DIM;
      float* ag = agg + (size_t)d * DIM;
#pragma unroll
      for (int ni = 0; ni < 4; ++ni) {
        int col = wn * 64 + ni * 16 + (l & 15);
        float v = acc[mi][ni][rr] + bf2f(xa[col]) + bf2f(xb[col]);
        unsafeAtomicAdd(ag + col, fmaxf(v, 0.0f));
      }
    }
}

// ---------------- node: out = relu( agg@W2b^T + Yx ) ----------------
__global__ __launch_bounds__(256, 2) void node_kernel(
    const float* __restrict__ agg, const unsigned short* __restrict__ Wt,
    const unsigned short* __restrict__ Yx, float* __restrict__ out) {
  __shared__ __align__(16) unsigned short As[128 * 128];
  __shared__ __align__(16) unsigned short Bs[128 * 128];
  const int t = threadIdx.x, l = t & 63, w = t >> 6, wm = w >> 1, wn = w & 1;
  const int n0 = blockIdx.x * 128;
#pragma unroll
  for (int i = 0; i < 16; ++i) {
    int idx = i * 256 + t;
    int row = idx >> 5;
    int c = (idx & 31) * 4;
    int n = n0 + row; if (n >= NNODES) n = NNODES - 1;
    float4 f = *(const float4*)(agg + (size_t)n * DIM + c);
    u32x2 g = {cvtpk(f.x, f.y), cvtpk(f.z, f.w)};
    *(u32x2*)(As + (row * 128 + (c ^ ((row & 7) << 3)))) = g;
  }
  {
    const u16x8* wsrc = (const u16x8*)(Wt + (size_t)4 * 16384);   // W2 agg-segment
    u16x8* bdst = (u16x8*)Bs;
#pragma unroll
    for (int i = 0; i < 8; ++i) bdst[t + i * 256] = wsrc[t + i * 256];
  }
  __syncthreads();
  f32x4 acc[4][4] = {};
  mfma128(As, Bs, acc, wm, wn, l);
#pragma unroll
  for (int mi = 0; mi < 4; ++mi)
#pragma unroll
    for (int rr = 0; rr < 4; ++rr) {
      int m = wm * 64 + mi * 16 + (l >> 4) * 4 + rr;
      int n = n0 + m;
      if (n < NNODES) {
        float* orow = out + (size_t)n * DIM;
#pragma unroll
        for (int ni = 0; ni < 4; ++ni) {
          int col = wn * 64 + ni * 16 + (l & 15);
          float v = acc[mi][ni][rr] + bf2f(Yx[(size_t)n * DIM + col]);
          orow[col] = fmaxf(v, 0.0f);
        }
      }
    }
}

extern "C" void kernel_launch(void* const* d_in, const int* in_sizes, int n_in,
                              void* d_out, int out_size, void* d_ws, size_t ws_size,
                              hipStream_t stream) {
  const float* x   = (const float*)d_in[0];
  const int* ei    = (const int*)d_in[1];
  const float* ea  = (const float*)d_in[2];
  const float* u   = (const float*)d_in[3];
  const int* batch = (const int*)d_in[4];
  const float* W1  = (const float*)d_in[5];
  const float* b1  = (const float*)d_in[6];
  const float* W2  = (const float*)d_in[7];
  const float* b2  = (const float*)d_in[8];
  float* out = (float*)d_out;
  const int* srcI = ei;
  const int* dstI = ei + NEDGES;

  const size_t XAD_B = (size_t)NNODES * DIM * 2;        // 12.8 MB each (bf16)
  const size_t U_B   = (size_t)64 * DIM * 4;
  const size_t WT_B  = (size_t)5 * 16384 * 2;           // 160 KB
  const size_t MSG_B = (size_t)NEDGES * DIM * 2;        // 204.8 MB (bf16, L3-resident)
  const size_t CNT_B = (size_t)(NNODES + 64) * 4;
  const size_t ORD_B = (size_t)NEDGES * 4;              // 3.2 MB
  const size_t BS_B  = 4096;
  const size_t need_base = 3 * XAD_B + 2 * U_B + WT_B;
  const size_t need_sort = need_base + MSG_B + 2 * CNT_B + ORD_B + 2 * BS_B;  // ~245 MB

  char* p = (char*)d_ws;
  unsigned short* Xad = (unsigned short*)p; p += XAD_B;
  unsigned short* Xb  = (unsigned short*)p; p += XAD_B;
  unsigned short* Yx  = (unsigned short*)p; p += XAD_B;
  float* Ud = (float*)p; p += U_B;
  float* Uc = (float*)p; p += U_B;
  unsigned short* Wt = (unsigned short*)p; p += WT_B;
  unsigned short* msg = (unsigned short*)p; p += MSG_B;
  int* count  = (int*)p; p += CNT_B;
  int* rowptr = (int*)p; p += CNT_B;
  int* order  = (int*)p; p += ORD_B;
  int* bsum = (int*)p; p += BS_B;
  int* bpre = (int*)p;

  float* agg = out;   // aggB writes all rows; node block reads/writes its own 128-row slice
  const int nAgg4 = NNODES * DIM / 4;

  if (ws_size >= need_sort) {
    zero_kernel<<<256, 256, 0, stream>>>((float4*)agg, 0, count, NNODES + 64);
    hist_kernel<<<(NEDGES + 255) / 256, 256, 0, stream>>>(dstI, count);
    scan1_kernel<<<NSB, 256, 0, stream>>>(count, bsum);
    scan2_kernel<<<1, 256, 0, stream>>>(bsum, bpre);
    scan3_kernel<<<NSB, 256, 0, stream>>>(count, bpre, rowptr);
    scatter_kernel<<<(NEDGES + 255) / 256, 256, 0, stream>>>(dstI, rowptr, order);
    wconv_p0_kernel<<<352, 256, 0, stream>>>(W1, W2, u, b1, b2, Wt, Ud, Uc);
    p1_kernel<<<(NNODES + 127) / 128, 256, 0, stream>>>(x, batch, Wt, Ud, Uc, Xad, Xb, Yx);
    edgeA_kernel<<<NEDGES / 128, 256, 0, stream>>>(ea, srcI, dstI, Wt + 2 * 16384, Xad, Xb, msg);
    aggB_kernel<<<(NNODES + 15) / 16, 256, 0, stream>>>(msg, order, rowptr, agg);
    node_kernel<<<(NNODES + 127) / 128, 256, 0, stream>>>(agg, Wt, Yx, out);
  } else if (ws_size >= need_base) {
    zero_kernel<<<2048, 256, 0, stream>>>((float4*)agg, nAgg4, (int*)Ud, 0);
    wconv_p0_kernel<<<352, 256, 0, stream>>>(W1, W2, u, b1, b2, Wt, Ud, Uc);
    p1_kernel<<<(NNODES + 127) / 128, 256, 0, stream>>>(x, batch, Wt, Ud, Uc, Xad, Xb, Yx);
    edge_kernel<<<NEDGES / 128, 256, 0, stream>>>(ea, srcI, dstI, Wt + 2 * 16384, Xad, Xb, agg);
    node_kernel<<<(NNODES + 127) / 128, 256, 0, stream>>>(agg, Wt, Yx, out);
  }
}